// Round 2
// baseline (718.589 us; speedup 1.0000x reference)
//
#include <hip/hip_runtime.h>

#define TOKENS 8192
#define HIDDEN 2048
#define INTER  5632

typedef _Float16 f16x8 __attribute__((ext_vector_type(8)));
typedef float    f32x4 __attribute__((ext_vector_type(4)));

// async global->LDS, 16B per lane. LDS dest = wave-uniform base + lane*16.
__device__ __forceinline__ void async_copy16(const void* g, void* l) {
  __builtin_amdgcn_global_load_lds(
      (const __attribute__((address_space(1))) unsigned int*)g,
      (__attribute__((address_space(3))) unsigned int*)l, 16, 0, 0);
}

#define BAR   __builtin_amdgcn_s_barrier()
#define SB0   __builtin_amdgcn_sched_barrier(0)
#define LGKM0 do { asm volatile("s_waitcnt lgkmcnt(0)" ::: "memory"); SB0; } while (0)
#define WAITVM(n) asm volatile("s_waitcnt vmcnt(" #n ")" ::: "memory")
#define PRIO(x) __builtin_amdgcn_s_setprio(x)

// ---------------- producers (unchanged, verified) ----------------

// x [T,H] fp32 -> staged [T/128][H/8][128][8] f16
__global__ void k_convert_x(const float* __restrict__ x, _Float16* __restrict__ xs) {
  const int kb = blockIdx.x;            // H/8 = 256
  const int mt = blockIdx.y;            // T/128 = 64
  const int m  = threadIdx.x;           // 128
  const float* src = x + (size_t)(mt * 128 + m) * HIDDEN + kb * 8;
  float4 f0 = *(const float4*)src;
  float4 f1 = *(const float4*)(src + 4);
  f16x8 v;
  v[0] = (_Float16)f0.x; v[1] = (_Float16)f0.y; v[2] = (_Float16)f0.z; v[3] = (_Float16)f0.w;
  v[4] = (_Float16)f1.x; v[5] = (_Float16)f1.y; v[6] = (_Float16)f1.z; v[7] = (_Float16)f1.w;
  *(f16x8*)(xs + ((size_t)(mt * 256 + kb) * 128 + m) * 8) = v;
}

// GPTQ dequant: qweight [K/8,N] int32 -> staged [K/8][N][8] f16
__global__ void k_dequant(const unsigned int* __restrict__ qw,
                          const unsigned int* __restrict__ qz,
                          const float* __restrict__ sc,
                          _Float16* __restrict__ out, int N, int N8) {
  const int n  = blockIdx.x * 256 + threadIdx.x;
  const int k8 = blockIdx.y;
  const int g  = k8 >> 4;
  unsigned int q  = qw[(size_t)k8 * N + n];
  unsigned int zw = qz[(size_t)g * N8 + (n >> 3)];
  int   z1 = (int)((zw >> ((n & 7) * 4)) & 0xFu) + 1;
  float s  = sc[(size_t)g * N + n];
  f16x8 w;
#pragma unroll
  for (int j = 0; j < 8; ++j)
    w[j] = (_Float16)((float)((int)((q >> (4 * j)) & 0xFu) - z1) * s);
  *(f16x8*)(out + ((size_t)k8 * N + n) * 8) = w;
}

// ---------------- GEMM1: m201 geometry, B-tile = [128 gate | 128 up] ----------------
// 512 thr = 8 waves (2M x 4N), per-wave 128x64, BK=64, NT=32 K-tiles.
// Waves wn<2 compute gate (cols 0..127 of B-tile), wn>=2 compute up (cols 128..255,
// same 128 INTER columns). Main loop is the verified k_gemm_down schedule verbatim
// (A=4 + B=4 stage loads per K-tile, WAITVM(8) at ph4/ph8).
// Epilogue: up-waves push acc through LDS; gate-waves combine silu(g)*u and store hs.
// Swizzle: B-panel-per-XCD (nt-chunked): each XCD keeps ~6 x 1MB B-panels L2-resident,
// all XCDs sweep the same A-panel in sync (A served by L3).
__global__ __launch_bounds__(512, 1)
void k_gemm_gateup(const _Float16* __restrict__ xs,
                   const _Float16* __restrict__ wg,
                   const _Float16* __restrict__ wu,
                   _Float16* __restrict__ hs) {
  extern __shared__ _Float16 lds[];
  _Float16* A0 = lds;            // [2 half][8 kb][128][8] = 16384 f16
  _Float16* A1 = lds + 16384;
  _Float16* B0 = lds + 32768;    // [8 kb][256][8] = 16384 f16 (gate|up)
  _Float16* B1 = lds + 49152;

  const int bid  = blockIdx.x;                    // 1408 = 8*176, %8==0
  const int wgid = (bid & 7) * 176 + (bid >> 3);  // XCD-chunked, bijective
  const int nt = wgid >> 5, mt = wgid & 31;       // nt in [0,44): consecutive blocks share B-panel

  const int tid  = threadIdx.x;
  const int wave = tid >> 6, lane = tid & 63;
  const int wm = wave >> 2, wn = wave & 3;        // 2M x 4N
  const int row16 = lane >> 4, col = lane & 15;

  int afo[8], bfo[4];
#pragma unroll
  for (int i = 0; i < 8; ++i)
    afo[i] = wm * 8192 + row16 * 1024 + (i * 16 + col) * 8;
#pragma unroll
  for (int i = 0; i < 4; ++i)
    bfo[i] = row16 * 2048 + (wn * 64 + i * 16 + col) * 8;

  const f32x4 zero = {0.f, 0.f, 0.f, 0.f};
  f32x4 acc[8][4];
#pragma unroll
  for (int i = 0; i < 8; ++i)
#pragma unroll
    for (int j = 0; j < 4; ++j) acc[i][j] = zero;

  f16x8 af[4][2], bf[4][2];

#define GU_LOAD_A(AP, mh) \
  _Pragma("unroll") for (int mi_ = 0; mi_ < 4; ++mi_) \
  _Pragma("unroll") for (int ks_ = 0; ks_ < 2; ++ks_) \
    af[mi_][ks_] = *(const f16x8*)((AP) + afo[(mh) * 4 + mi_] + ks_ * 4096);

#define GU_LOAD_B(BP, nh) \
  _Pragma("unroll") for (int ni_ = 0; ni_ < 2; ++ni_) \
  _Pragma("unroll") for (int ks_ = 0; ks_ < 2; ++ks_) \
    bf[(nh) * 2 + ni_][ks_] = *(const f16x8*)((BP) + bfo[(nh) * 2 + ni_] + ks_ * 8192);

#define GU_MFMA(mh, nh) \
  _Pragma("unroll") for (int mi_ = 0; mi_ < 4; ++mi_) \
  _Pragma("unroll") for (int ni_ = 0; ni_ < 2; ++ni_) \
  _Pragma("unroll") for (int ks_ = 0; ks_ < 2; ++ks_) \
    acc[(mh) * 4 + mi_][(nh) * 2 + ni_] = __builtin_amdgcn_mfma_f32_16x16x32_f16( \
        af[mi_][ks_], bf[(nh) * 2 + ni_][ks_], acc[(mh) * 4 + mi_][(nh) * 2 + ni_], 0, 0, 0);

#define GU_STAGE_A(AP, kt) do { const int kt_ = (kt); \
  _Pragma("unroll") for (int q_ = 0; q_ < 4; ++q_) { \
    const int i_ = q_ * 512 + tid; \
    async_copy16(xs + (size_t)(((2 * mt + (i_ >> 10)) * 256 + kt_ * 8 + ((i_ >> 7) & 7)) * 128 + (i_ & 127)) * 8, \
                 (char*)(AP) + q_ * 8192 + wave * 1024); } } while (0)

// B-tile chunk i: kb = i>>8, packed col c = i&255 (= tid&255, wave-uniform matrix select),
// matrix = c>>7 (0=gate, 1=up), col-in-matrix = c&127.
#define GU_STAGE_B(BP, kt) do { const int kt_ = (kt); \
  _Pragma("unroll") for (int q_ = 0; q_ < 4; ++q_) { \
    const int i_ = q_ * 512 + tid; \
    const int kb_ = i_ >> 8, c_ = i_ & 255; \
    const _Float16* bsrc_ = (c_ & 128) ? wu : wg; \
    async_copy16(bsrc_ + (size_t)((kt_ * 8 + kb_) * INTER + nt * 128 + (c_ & 127)) * 8, \
                 (char*)(BP) + q_ * 8192 + wave * 1024); } } while (0)

  // prologue: tile0 -> buf0 (8 loads), tile1 -> buf1 (8 loads)
  GU_STAGE_B(B0, 0); GU_STAGE_A(A0, 0);
  GU_STAGE_B(B1, 1); GU_STAGE_A(A1, 1);
  WAITVM(8);          // tile0 complete; tile1's 8 stay in flight
  BAR; SB0;

  for (int t2 = 0; t2 < 16; ++t2) {
    const int e2 = (2 * t2 + 2 < 32) ? 2 * t2 + 2 : 31;   // clamped dummies keep vmcnt uniform
    const int o2 = (2 * t2 + 3 < 32) ? 2 * t2 + 3 : 31;
    // ph1: E Q(0,0)
    GU_LOAD_A(A0, 0); GU_LOAD_B(B0, 0);
    BAR; LGKM0; PRIO(1); GU_MFMA(0, 0); PRIO(0); BAR; SB0;
    // ph2: E Q(0,1)
    GU_LOAD_B(B0, 1);
    BAR; LGKM0; PRIO(1); GU_MFMA(0, 1); PRIO(0); BAR; SB0;
    // ph3: E Q(1,0) (B nh0 kept in regs)
    GU_LOAD_A(A0, 1); GU_STAGE_B(B0, e2);
    BAR; LGKM0; PRIO(1); GU_MFMA(1, 0); PRIO(0); BAR; SB0;
    // ph4: E Q(1,1) + counted wait (tile O resident)
    GU_STAGE_A(A0, e2);
    BAR; LGKM0; PRIO(1); GU_MFMA(1, 1); PRIO(0); WAITVM(8); BAR; SB0;
    // ph5: O Q(0,0)
    GU_LOAD_A(A1, 0); GU_LOAD_B(B1, 0);
    BAR; LGKM0; PRIO(1); GU_MFMA(0, 0); PRIO(0); BAR; SB0;
    // ph6: O Q(0,1)
    GU_LOAD_B(B1, 1);
    BAR; LGKM0; PRIO(1); GU_MFMA(0, 1); PRIO(0); BAR; SB0;
    // ph7: O Q(1,0)
    GU_LOAD_A(A1, 1); GU_STAGE_B(B1, o2);
    BAR; LGKM0; PRIO(1); GU_MFMA(1, 0); PRIO(0); BAR; SB0;
    // ph8: O Q(1,1) + counted wait (tile E+2 resident)
    GU_STAGE_A(A1, o2);
    BAR; LGKM0; PRIO(1); GU_MFMA(1, 1); PRIO(0); WAITVM(8); BAR; SB0;
  }
  WAITVM(0);          // drain dummy stages (they target LDS) before reuse
  __syncthreads();

  // epilogue: up-waves (wn>=2) push acc via LDS; partner gate-wave (wm, wn&1) combines.
  // layout: [pair 0..3][chunk 0..31][lane 0..63][f32x4] -> conflict-free b128.
  {
    float* xls = (float*)lds;
    const int pairIdx = wm * 2 + (wn & 1);
    if (wn >= 2) {
      float* dst = xls + (size_t)pairIdx * 8192 + lane * 4;
#pragma unroll
      for (int mi = 0; mi < 8; ++mi)
#pragma unroll
        for (int ni = 0; ni < 4; ++ni)
          *(f32x4*)(dst + (mi * 4 + ni) * 256) = acc[mi][ni];
    }
    __syncthreads();
    if (wn < 2) {
      const float* srcp = xls + (size_t)pairIdx * 8192 + lane * 4;
#pragma unroll
      for (int mi = 0; mi < 8; ++mi)
#pragma unroll
        for (int ni = 0; ni < 4; ++ni) {
          const f32x4 uv = *(const f32x4*)(srcp + (mi * 4 + ni) * 256);
          const int kg = nt * 128 + wn * 64 + ni * 16 + col;   // global INTER col
          const size_t base = ((size_t)(mt * 2 + wm) * 704 + (kg >> 3)) * 1024 + (kg & 7);
#pragma unroll
          for (int r = 0; r < 4; ++r) {
            const float g = acc[mi][ni][r];
            const float h = g / (1.f + __expf(-g)) * uv[r];
            const int mloc = mi * 16 + row16 * 4 + r;
            hs[base + (size_t)mloc * 8] = (_Float16)h;
          }
        }
    }
  }
#undef GU_LOAD_A
#undef GU_LOAD_B
#undef GU_MFMA
#undef GU_STAGE_A
#undef GU_STAGE_B
}

// ---------------- GEMM2: 8-phase counted-vmcnt, tile 256x256 (unchanged, improved last round) --
__global__ __launch_bounds__(512, 1)
void k_gemm_down(const _Float16* __restrict__ hs,
                 const _Float16* __restrict__ wd,
                 float* __restrict__ out) {
  extern __shared__ _Float16 lds[];
  _Float16* A0 = lds;            // [2 half][8 kb][128][8] = 16384 f16
  _Float16* A1 = lds + 16384;
  _Float16* B0 = lds + 32768;    // [8 kb][256][8] = 16384 f16
  _Float16* B1 = lds + 49152;

  const int bid  = blockIdx.x;                   // 256 = 8*32, %8==0
  const int wgid = (bid & 7) * 32 + (bid >> 3);  // XCD-chunked swizzle
  const int nt = wgid >> 5, mt = wgid & 31;      // each XCD owns one B-panel (2.9MB, L2-fit)

  const int tid  = threadIdx.x;
  const int wave = tid >> 6, lane = tid & 63;
  const int wm = wave >> 2, wn = wave & 3;       // 2M x 4N
  const int row16 = lane >> 4, col = lane & 15;

  int afo[8], bfo[4];
#pragma unroll
  for (int i = 0; i < 8; ++i)
    afo[i] = wm * 8192 + row16 * 1024 + (i * 16 + col) * 8;
#pragma unroll
  for (int i = 0; i < 4; ++i)
    bfo[i] = row16 * 2048 + (wn * 64 + i * 16 + col) * 8;

  const f32x4 zero = {0.f, 0.f, 0.f, 0.f};
  f32x4 acc[8][4];
#pragma unroll
  for (int i = 0; i < 8; ++i)
#pragma unroll
    for (int j = 0; j < 4; ++j) acc[i][j] = zero;

  f16x8 af[4][2], bf[4][2];

#define DN_LOAD_A(AP, mh) \
  _Pragma("unroll") for (int mi_ = 0; mi_ < 4; ++mi_) \
  _Pragma("unroll") for (int ks_ = 0; ks_ < 2; ++ks_) \
    af[mi_][ks_] = *(const f16x8*)((AP) + afo[(mh) * 4 + mi_] + ks_ * 4096);

#define DN_LOAD_B(BP, nh) \
  _Pragma("unroll") for (int ni_ = 0; ni_ < 2; ++ni_) \
  _Pragma("unroll") for (int ks_ = 0; ks_ < 2; ++ks_) \
    bf[(nh) * 2 + ni_][ks_] = *(const f16x8*)((BP) + bfo[(nh) * 2 + ni_] + ks_ * 8192);

#define DN_MFMA(mh, nh) \
  _Pragma("unroll") for (int mi_ = 0; mi_ < 4; ++mi_) \
  _Pragma("unroll") for (int ni_ = 0; ni_ < 2; ++ni_) \
  _Pragma("unroll") for (int ks_ = 0; ks_ < 2; ++ks_) \
    acc[(mh) * 4 + mi_][(nh) * 2 + ni_] = __builtin_amdgcn_mfma_f32_16x16x32_f16( \
        af[mi_][ks_], bf[(nh) * 2 + ni_][ks_], acc[(mh) * 4 + mi_][(nh) * 2 + ni_], 0, 0, 0);

#define DN_STAGE_A(AP, kt) do { const int kt_ = (kt); \
  _Pragma("unroll") for (int q_ = 0; q_ < 4; ++q_) { \
    const int i_ = q_ * 512 + tid; \
    async_copy16(hs + (size_t)(((2 * mt + (i_ >> 10)) * 704 + kt_ * 8 + ((i_ >> 7) & 7)) * 128 + (i_ & 127)) * 8, \
                 (char*)(AP) + q_ * 8192 + wave * 1024); } } while (0)

#define DN_STAGE_B(BP, kt) do { const int kt_ = (kt); \
  _Pragma("unroll") for (int q_ = 0; q_ < 4; ++q_) { \
    const int i_ = q_ * 512 + tid; \
    async_copy16(wd + (size_t)((kt_ * 8 + (i_ >> 8)) * HIDDEN + nt * 256 + (i_ & 255)) * 8, \
                 (char*)(BP) + q_ * 8192 + wave * 1024); } } while (0)

  // prologue: tile0 -> buf0 (8 loads), tile1 -> buf1 (8 loads)
  DN_STAGE_B(B0, 0); DN_STAGE_A(A0, 0);
  DN_STAGE_B(B1, 1); DN_STAGE_A(A1, 1);
  WAITVM(8);          // tile0 complete; tile1's 8 stay in flight
  BAR; SB0;

  for (int t2 = 0; t2 < 44; ++t2) {
    const int e2 = (2 * t2 + 2 < 88) ? 2 * t2 + 2 : 87;
    const int o2 = (2 * t2 + 3 < 88) ? 2 * t2 + 3 : 87;
    // ph1: E Q(0,0)
    DN_LOAD_A(A0, 0); DN_LOAD_B(B0, 0);
    BAR; LGKM0; PRIO(1); DN_MFMA(0, 0); PRIO(0); BAR; SB0;
    // ph2: E Q(0,1)
    DN_LOAD_B(B0, 1);
    BAR; LGKM0; PRIO(1); DN_MFMA(0, 1); PRIO(0); BAR; SB0;
    // ph3: E Q(1,0) (B nh0 kept in regs)
    DN_LOAD_A(A0, 1); DN_STAGE_B(B0, e2);
    BAR; LGKM0; PRIO(1); DN_MFMA(1, 0); PRIO(0); BAR; SB0;
    // ph4: E Q(1,1) + counted wait (tile O resident)
    DN_STAGE_A(A0, e2);
    BAR; LGKM0; PRIO(1); DN_MFMA(1, 1); PRIO(0); WAITVM(8); BAR; SB0;
    // ph5: O Q(0,0)
    DN_LOAD_A(A1, 0); DN_LOAD_B(B1, 0);
    BAR; LGKM0; PRIO(1); DN_MFMA(0, 0); PRIO(0); BAR; SB0;
    // ph6: O Q(0,1)
    DN_LOAD_B(B1, 1);
    BAR; LGKM0; PRIO(1); DN_MFMA(0, 1); PRIO(0); BAR; SB0;
    // ph7: O Q(1,0)
    DN_LOAD_A(A1, 1); DN_STAGE_B(B1, o2);
    BAR; LGKM0; PRIO(1); DN_MFMA(1, 0); PRIO(0); BAR; SB0;
    // ph8: O Q(1,1) + counted wait (tile E+2 resident)
    DN_STAGE_A(A1, o2);
    BAR; LGKM0; PRIO(1); DN_MFMA(1, 1); PRIO(0); WAITVM(8); BAR; SB0;
  }
  WAITVM(0);

#pragma unroll
  for (int mi = 0; mi < 8; ++mi)
#pragma unroll
    for (int ni = 0; ni < 4; ++ni) {
      const int n = nt * 256 + wn * 64 + ni * 16 + col;
#pragma unroll
      for (int r = 0; r < 4; ++r) {
        const int m = mt * 256 + wm * 128 + mi * 16 + row16 * 4 + r;
        out[(size_t)m * HIDDEN + n] = acc[mi][ni][r];
      }
    }
#undef DN_LOAD_A
#undef DN_LOAD_B
#undef DN_MFMA
#undef DN_STAGE_A
#undef DN_STAGE_B
}

extern "C" void kernel_launch(void* const* d_in, const int* in_sizes, int n_in,
                              void* d_out, int out_size, void* d_ws, size_t ws_size,
                              hipStream_t stream) {
  (void)in_sizes; (void)n_in; (void)out_size; (void)ws_size;
  const float*        x  = (const float*)d_in[0];
  const unsigned int* gq = (const unsigned int*)d_in[1];
  const unsigned int* gz = (const unsigned int*)d_in[2];
  const float*        gs = (const float*)d_in[3];
  const unsigned int* uq = (const unsigned int*)d_in[4];
  const unsigned int* uz = (const unsigned int*)d_in[5];
  const float*        us = (const float*)d_in[6];
  const unsigned int* dq = (const unsigned int*)d_in[7];
  const unsigned int* dz = (const unsigned int*)d_in[8];
  const float*        ds = (const float*)d_in[9];
  float* out = (float*)d_out;

  // workspace layout (bytes):
  // xs  [0, 32MB)   x staged f16
  // wgd [32MB, +22MB) wud [+22MB) wdd [+22MB)  dequanted weights, staged f16
  // hs  [+88MB)     h staged f16   -> total ~186MB
  char* ws = (char*)d_ws;
  _Float16* xs  = (_Float16*)ws;
  _Float16* wgd = (_Float16*)(ws + (size_t)TOKENS * HIDDEN * 2);
  _Float16* wud = wgd + (size_t)HIDDEN * INTER;
  _Float16* wdd = wud + (size_t)HIDDEN * INTER;
  _Float16* hs  = wdd + (size_t)INTER * HIDDEN;

  static bool attr_set = false;
  if (!attr_set) {
    hipFuncSetAttribute((const void*)k_gemm_gateup,
                        hipFuncAttributeMaxDynamicSharedMemorySize, 131072);
    hipFuncSetAttribute((const void*)k_gemm_down,
                        hipFuncAttributeMaxDynamicSharedMemorySize, 131072);
    attr_set = true;
  }

  k_convert_x<<<dim3(HIDDEN / 8, TOKENS / 128), 128, 0, stream>>>(x, xs);
  k_dequant<<<dim3(INTER / 256, HIDDEN / 8), 256, 0, stream>>>(gq, gz, gs, wgd, INTER, INTER / 8);
  k_dequant<<<dim3(INTER / 256, HIDDEN / 8), 256, 0, stream>>>(uq, uz, us, wud, INTER, INTER / 8);
  k_dequant<<<dim3(HIDDEN / 256, INTER / 8), 256, 0, stream>>>(dq, dz, ds, wdd, HIDDEN, HIDDEN / 8);
  k_gemm_gateup<<<dim3(1408), 512, 131072, stream>>>(xs, wgd, wud, hs);
  k_gemm_down<<<dim3(256), 512, 131072, stream>>>(hs, wdd, out);
}

// Round 3
// 661.336 us; speedup vs baseline: 1.0866x; 1.0866x over previous
//
#include <hip/hip_runtime.h>

#define TOKENS 8192
#define HIDDEN 2048
#define INTER  5632

typedef _Float16 f16x8 __attribute__((ext_vector_type(8)));
typedef float    f32x4 __attribute__((ext_vector_type(4)));

// async global->LDS, 16B per lane. LDS dest = wave-uniform base + lane*16.
__device__ __forceinline__ void async_copy16(const void* g, void* l) {
  __builtin_amdgcn_global_load_lds(
      (const __attribute__((address_space(1))) unsigned int*)g,
      (__attribute__((address_space(3))) unsigned int*)l, 16, 0, 0);
}

#define BAR   __builtin_amdgcn_s_barrier()
#define SB0   __builtin_amdgcn_sched_barrier(0)
#define LGKM0 do { asm volatile("s_waitcnt lgkmcnt(0)" ::: "memory"); SB0; } while (0)
#define WAITVM(n) asm volatile("s_waitcnt vmcnt(" #n ")" ::: "memory")
#define PRIO(x) __builtin_amdgcn_s_setprio(x)

// ---------------- producers ----------------

// x [T,H] fp32 -> staged [T/128][H/8][128][8] f16.
// Coalesced rewrite: tile 32 m x 64 k per block; float4 row reads -> LDS
// transpose (lt[k][m], pitch 33: phase-1 writes 2-way conflict (free),
// phase-2 reads conflict-free) -> contiguous f16x8 writes.
__global__ __launch_bounds__(256)
void k_convert_x(const float* __restrict__ x, _Float16* __restrict__ xs) {
  __shared__ float lt[64 * 33];
  const int kb0  = blockIdx.x;          // H/64 = 32
  const int mt32 = blockIdx.y;          // T/32 = 256
  const int t    = threadIdx.x;

  const int m_l  = t >> 3;              // 0..31
  const int k4a  = t & 7;               // 0..7
  const float* row = x + (size_t)(mt32 * 32 + m_l) * HIDDEN + kb0 * 64;
#pragma unroll
  for (int h = 0; h < 2; ++h) {
    const int k4 = k4a + h * 8;         // 0..15
    const float4 f = *(const float4*)(row + k4 * 4);
    lt[(k4 * 4 + 0) * 33 + m_l] = f.x;
    lt[(k4 * 4 + 1) * 33 + m_l] = f.y;
    lt[(k4 * 4 + 2) * 33 + m_l] = f.z;
    lt[(k4 * 4 + 3) * 33 + m_l] = f.w;
  }
  __syncthreads();

  const int kb_l = t >> 5;              // 0..7
  const int m_o  = t & 31;              // 0..31
  f16x8 v;
#pragma unroll
  for (int j = 0; j < 8; ++j)
    v[j] = (_Float16)lt[(kb_l * 8 + j) * 33 + m_o];
  const int kb   = kb0 * 8 + kb_l;      // 0..255
  const int mt128 = mt32 >> 2;
  const int m128  = (mt32 & 3) * 32 + m_o;
  *(f16x8*)(xs + ((size_t)(mt128 * 256 + kb) * 128 + m128) * 8) = v;
}

// GPTQ dequant: qweight [K/8,N] int32 -> staged [K/8][N][8] f16
__global__ void k_dequant(const unsigned int* __restrict__ qw,
                          const unsigned int* __restrict__ qz,
                          const float* __restrict__ sc,
                          _Float16* __restrict__ out, int N, int N8) {
  const int n  = blockIdx.x * 256 + threadIdx.x;
  const int k8 = blockIdx.y;
  const int g  = k8 >> 4;
  unsigned int q  = qw[(size_t)k8 * N + n];
  unsigned int zw = qz[(size_t)g * N8 + (n >> 3)];
  int   z1 = (int)((zw >> ((n & 7) * 4)) & 0xFu) + 1;
  float s  = sc[(size_t)g * N + n];
  f16x8 w;
#pragma unroll
  for (int j = 0; j < 8; ++j)
    w[j] = (_Float16)((float)((int)((q >> (4 * j)) & 0xFu) - z1) * s);
  *(f16x8*)(out + ((size_t)k8 * N + n) * 8) = w;
}

// ---------------- GEMM1: round-0 structure (2 blocks/CU TLP, 128x128 dual-B) ----------------
// block: 256 thr = 4 waves (2x2), tile 128x128, BK=64, MFMA 16x16x32 f16.
// TLP (2 blocks/CU) covers the per-tile barrier drain; measured 52% MfmaUtil.
__global__ __launch_bounds__(256, 2)
void k_gemm_gateup(const _Float16* __restrict__ xs,
                   const _Float16* __restrict__ wg,
                   const _Float16* __restrict__ wu,
                   _Float16* __restrict__ hs) {
  __shared__ _Float16 lds[3 * 8192];    // A | Bg | Bu, each [8 kb][128][8] = 16KB
  _Float16* Al  = lds;
  _Float16* Bgl = lds + 8192;
  _Float16* Bul = lds + 16384;
  const int nt = blockIdx.x, mt = blockIdx.y;
  const int tid = threadIdx.x;
  const int wave = tid >> 6, lane = tid & 63;
  const int wm = wave >> 1, wn = wave & 1;
  const int row16 = lane >> 4, col = lane & 15;
  const int slot = wave * 4;

  const _Float16* gA = xs + (size_t)mt * 256 * 1024;   // + kit*8192 per iter

  int afo[4], bfo[4];
#pragma unroll
  for (int i = 0; i < 4; ++i) {
    afo[i] = (row16 * 128 + wm * 64 + i * 16 + col) * 8;
    bfo[i] = (row16 * 128 + wn * 64 + i * 16 + col) * 8;
  }

  const f32x4 zero = {0.f, 0.f, 0.f, 0.f};
  f32x4 accg[4][4], accu[4][4];
#pragma unroll
  for (int i = 0; i < 4; ++i)
#pragma unroll
    for (int j = 0; j < 4; ++j) { accg[i][j] = zero; accu[i][j] = zero; }

  for (int kit = 0; kit < HIDDEN / 64; ++kit) {        // 32 iters
    __syncthreads();                                    // protect LDS reuse
#pragma unroll
    for (int q = 0; q < 4; ++q) {
      const int c = (slot + q) * 64 + lane;             // 16B chunk id in tile
      async_copy16(gA + (size_t)kit * 8192 + (size_t)c * 8,
                   (char*)Al + (size_t)(slot + q) * 1024);
      const int kbl = c >> 7, cc = c & 127;
      const size_t bo = ((size_t)(kit * 8 + kbl) * INTER + nt * 128 + cc) * 8;
      async_copy16(wg + bo, (char*)Bgl + (size_t)(slot + q) * 1024);
      async_copy16(wu + bo, (char*)Bul + (size_t)(slot + q) * 1024);
    }
    __syncthreads();                                    // drains vmcnt(0)
#pragma unroll
    for (int ks = 0; ks < 2; ++ks) {
      const int kadd = ks * 4096;                       // +4 kb rows
      f16x8 af[4], bg[4], bu[4];
#pragma unroll
      for (int i = 0; i < 4; ++i) {
        af[i] = *(const f16x8*)(Al  + kadd + afo[i]);
        bg[i] = *(const f16x8*)(Bgl + kadd + bfo[i]);
        bu[i] = *(const f16x8*)(Bul + kadd + bfo[i]);
      }
#pragma unroll
      for (int mi = 0; mi < 4; ++mi)
#pragma unroll
        for (int ni = 0; ni < 4; ++ni) {
          accg[mi][ni] = __builtin_amdgcn_mfma_f32_16x16x32_f16(af[mi], bg[ni], accg[mi][ni], 0, 0, 0);
          accu[mi][ni] = __builtin_amdgcn_mfma_f32_16x16x32_f16(af[mi], bu[ni], accu[mi][ni], 0, 0, 0);
        }
    }
  }
  // epilogue: h = g*sigmoid(g)*u, scatter into staged layout (2B stores)
#pragma unroll
  for (int mi = 0; mi < 4; ++mi)
#pragma unroll
    for (int ni = 0; ni < 4; ++ni) {
      const int kg = nt * 128 + wn * 64 + ni * 16 + col;   // global INTER idx
      const size_t base = (size_t)(mt * (INTER / 8) + (kg >> 3)) * 1024 + (kg & 7);
#pragma unroll
      for (int r = 0; r < 4; ++r) {
        float g = accg[mi][ni][r], u = accu[mi][ni][r];
        float h = g / (1.f + __expf(-g)) * u;
        const int ml = wm * 64 + mi * 16 + row16 * 4 + r;
        hs[base + (size_t)ml * 8] = (_Float16)h;
      }
    }
}

// ---------------- GEMM2: 8-phase counted-vmcnt, tile 256x256 (proven, unchanged) ----------------
__global__ __launch_bounds__(512, 1)
void k_gemm_down(const _Float16* __restrict__ hs,
                 const _Float16* __restrict__ wd,
                 float* __restrict__ out) {
  extern __shared__ _Float16 lds[];
  _Float16* A0 = lds;            // [2 half][8 kb][128][8] = 16384 f16
  _Float16* A1 = lds + 16384;
  _Float16* B0 = lds + 32768;    // [8 kb][256][8] = 16384 f16
  _Float16* B1 = lds + 49152;

  const int bid  = blockIdx.x;                   // 256 = 8*32, %8==0
  const int wgid = (bid & 7) * 32 + (bid >> 3);  // XCD-chunked swizzle
  const int nt = wgid >> 5, mt = wgid & 31;      // each XCD owns one B-panel (L2-fit)

  const int tid  = threadIdx.x;
  const int wave = tid >> 6, lane = tid & 63;
  const int wm = wave >> 2, wn = wave & 3;       // 2M x 4N
  const int row16 = lane >> 4, col = lane & 15;

  int afo[8], bfo[4];
#pragma unroll
  for (int i = 0; i < 8; ++i)
    afo[i] = wm * 8192 + row16 * 1024 + (i * 16 + col) * 8;
#pragma unroll
  for (int i = 0; i < 4; ++i)
    bfo[i] = row16 * 2048 + (wn * 64 + i * 16 + col) * 8;

  const f32x4 zero = {0.f, 0.f, 0.f, 0.f};
  f32x4 acc[8][4];
#pragma unroll
  for (int i = 0; i < 8; ++i)
#pragma unroll
    for (int j = 0; j < 4; ++j) acc[i][j] = zero;

  f16x8 af[4][2], bf[4][2];

#define DN_LOAD_A(AP, mh) \
  _Pragma("unroll") for (int mi_ = 0; mi_ < 4; ++mi_) \
  _Pragma("unroll") for (int ks_ = 0; ks_ < 2; ++ks_) \
    af[mi_][ks_] = *(const f16x8*)((AP) + afo[(mh) * 4 + mi_] + ks_ * 4096);

#define DN_LOAD_B(BP, nh) \
  _Pragma("unroll") for (int ni_ = 0; ni_ < 2; ++ni_) \
  _Pragma("unroll") for (int ks_ = 0; ks_ < 2; ++ks_) \
    bf[(nh) * 2 + ni_][ks_] = *(const f16x8*)((BP) + bfo[(nh) * 2 + ni_] + ks_ * 8192);

#define DN_MFMA(mh, nh) \
  _Pragma("unroll") for (int mi_ = 0; mi_ < 4; ++mi_) \
  _Pragma("unroll") for (int ni_ = 0; ni_ < 2; ++ni_) \
  _Pragma("unroll") for (int ks_ = 0; ks_ < 2; ++ks_) \
    acc[(mh) * 4 + mi_][(nh) * 2 + ni_] = __builtin_amdgcn_mfma_f32_16x16x32_f16( \
        af[mi_][ks_], bf[(nh) * 2 + ni_][ks_], acc[(mh) * 4 + mi_][(nh) * 2 + ni_], 0, 0, 0);

#define DN_STAGE_A(AP, kt) do { const int kt_ = (kt); \
  _Pragma("unroll") for (int q_ = 0; q_ < 4; ++q_) { \
    const int i_ = q_ * 512 + tid; \
    async_copy16(hs + (size_t)(((2 * mt + (i_ >> 10)) * 704 + kt_ * 8 + ((i_ >> 7) & 7)) * 128 + (i_ & 127)) * 8, \
                 (char*)(AP) + q_ * 8192 + wave * 1024); } } while (0)

#define DN_STAGE_B(BP, kt) do { const int kt_ = (kt); \
  _Pragma("unroll") for (int q_ = 0; q_ < 4; ++q_) { \
    const int i_ = q_ * 512 + tid; \
    async_copy16(wd + (size_t)((kt_ * 8 + (i_ >> 8)) * HIDDEN + nt * 256 + (i_ & 255)) * 8, \
                 (char*)(BP) + q_ * 8192 + wave * 1024); } } while (0)

  // prologue: tile0 -> buf0 (8 loads), tile1 -> buf1 (8 loads)
  DN_STAGE_B(B0, 0); DN_STAGE_A(A0, 0);
  DN_STAGE_B(B1, 1); DN_STAGE_A(A1, 1);
  WAITVM(8);          // tile0 complete; tile1's 8 stay in flight
  BAR; SB0;

  for (int t2 = 0; t2 < 44; ++t2) {
    const int e2 = (2 * t2 + 2 < 88) ? 2 * t2 + 2 : 87;
    const int o2 = (2 * t2 + 3 < 88) ? 2 * t2 + 3 : 87;
    // ph1: E Q(0,0)
    DN_LOAD_A(A0, 0); DN_LOAD_B(B0, 0);
    BAR; LGKM0; PRIO(1); DN_MFMA(0, 0); PRIO(0); BAR; SB0;
    // ph2: E Q(0,1)
    DN_LOAD_B(B0, 1);
    BAR; LGKM0; PRIO(1); DN_MFMA(0, 1); PRIO(0); BAR; SB0;
    // ph3: E Q(1,0)
    DN_LOAD_A(A0, 1); DN_STAGE_B(B0, e2);
    BAR; LGKM0; PRIO(1); DN_MFMA(1, 0); PRIO(0); BAR; SB0;
    // ph4: E Q(1,1) + counted wait (tile O resident)
    DN_STAGE_A(A0, e2);
    BAR; LGKM0; PRIO(1); DN_MFMA(1, 1); PRIO(0); WAITVM(8); BAR; SB0;
    // ph5: O Q(0,0)
    DN_LOAD_A(A1, 0); DN_LOAD_B(B1, 0);
    BAR; LGKM0; PRIO(1); DN_MFMA(0, 0); PRIO(0); BAR; SB0;
    // ph6: O Q(0,1)
    DN_LOAD_B(B1, 1);
    BAR; LGKM0; PRIO(1); DN_MFMA(0, 1); PRIO(0); BAR; SB0;
    // ph7: O Q(1,0)
    DN_LOAD_A(A1, 1); DN_STAGE_B(B1, o2);
    BAR; LGKM0; PRIO(1); DN_MFMA(1, 0); PRIO(0); BAR; SB0;
    // ph8: O Q(1,1) + counted wait (tile E+2 resident)
    DN_STAGE_A(A1, o2);
    BAR; LGKM0; PRIO(1); DN_MFMA(1, 1); PRIO(0); WAITVM(8); BAR; SB0;
  }
  WAITVM(0);

#pragma unroll
  for (int mi = 0; mi < 8; ++mi)
#pragma unroll
    for (int ni = 0; ni < 4; ++ni) {
      const int n = nt * 256 + wn * 64 + ni * 16 + col;
#pragma unroll
      for (int r = 0; r < 4; ++r) {
        const int m = mt * 256 + wm * 128 + mi * 16 + row16 * 4 + r;
        out[(size_t)m * HIDDEN + n] = acc[mi][ni][r];
      }
    }
#undef DN_LOAD_A
#undef DN_LOAD_B
#undef DN_MFMA
#undef DN_STAGE_A
#undef DN_STAGE_B
}

extern "C" void kernel_launch(void* const* d_in, const int* in_sizes, int n_in,
                              void* d_out, int out_size, void* d_ws, size_t ws_size,
                              hipStream_t stream) {
  (void)in_sizes; (void)n_in; (void)out_size; (void)ws_size;
  const float*        x  = (const float*)d_in[0];
  const unsigned int* gq = (const unsigned int*)d_in[1];
  const unsigned int* gz = (const unsigned int*)d_in[2];
  const float*        gs = (const float*)d_in[3];
  const unsigned int* uq = (const unsigned int*)d_in[4];
  const unsigned int* uz = (const unsigned int*)d_in[5];
  const float*        us = (const float*)d_in[6];
  const unsigned int* dq = (const unsigned int*)d_in[7];
  const unsigned int* dz = (const unsigned int*)d_in[8];
  const float*        ds = (const float*)d_in[9];
  float* out = (float*)d_out;

  // workspace layout (bytes):
  // xs  [0, 32MB)   x staged f16
  // wgd [32MB, +22MB) wud [+22MB) wdd [+22MB)  dequanted weights, staged f16
  // hs  [+88MB)     h staged f16   -> total ~186MB
  char* ws = (char*)d_ws;
  _Float16* xs  = (_Float16*)ws;
  _Float16* wgd = (_Float16*)(ws + (size_t)TOKENS * HIDDEN * 2);
  _Float16* wud = wgd + (size_t)HIDDEN * INTER;
  _Float16* wdd = wud + (size_t)HIDDEN * INTER;
  _Float16* hs  = wdd + (size_t)INTER * HIDDEN;

  static bool attr_set = false;
  if (!attr_set) {
    hipFuncSetAttribute((const void*)k_gemm_down,
                        hipFuncAttributeMaxDynamicSharedMemorySize, 131072);
    attr_set = true;
  }

  k_convert_x<<<dim3(HIDDEN / 64, TOKENS / 32), 256, 0, stream>>>(x, xs);
  k_dequant<<<dim3(INTER / 256, HIDDEN / 8), 256, 0, stream>>>(gq, gz, gs, wgd, INTER, INTER / 8);
  k_dequant<<<dim3(INTER / 256, HIDDEN / 8), 256, 0, stream>>>(uq, uz, us, wud, INTER, INTER / 8);
  k_dequant<<<dim3(HIDDEN / 256, INTER / 8), 256, 0, stream>>>(dq, dz, ds, wdd, HIDDEN, HIDDEN / 8);
  k_gemm_gateup<<<dim3(INTER / 128, TOKENS / 128), 256, 0, stream>>>(xs, wgd, wud, hs);
  k_gemm_down<<<dim3(256), 512, 131072, stream>>>(hs, wdd, out);
}